// Round 2
// baseline (385.809 us; speedup 1.0000x reference)
//
#include <hip/hip_runtime.h>
#include <hip/hip_cooperative_groups.h>

namespace cg = cooperative_groups;

// Tucker scoring: out[n] = sum_{p,q,r} U[i_n,p] V[j_n,q] W[k_n,r] G[p,q,r]
// P=Q=R=32, N=131072, num_time=5000.
//
// Round 6: single cooperative kernel, H never touches global memory.
//   Phase A: zero counts/ovf_cnt                         -> grid.sync
//   Phase B: scatter samples into per-k bins (CAP=128)   -> grid.sync
//   Phase C: each wave computes H[k] = G x_r W[k] straight into its private
//            4KB LDS row (no 20.5MB H global write + 20.5MB re-read).
//   Phase D: eval from LDS: 8 lanes x 8 samples per wave iteration,
//            branch-free clamped indices, record prefetch.
//   Overflow records are drained inside the group loop by the wave owning
//   that k (expected count 0 for uniform k).
// Each block owns 2 k-groups (grid = ceil(ngroups/2) = 625 blocks, 4 waves).
// Fallback to the previous 3-dispatch pipeline if cooperative launch fails.

#define BIN_CAP 128

// ---------------------------------------------------------------------------
// fused cooperative kernel
// ---------------------------------------------------------------------------
__global__ __launch_bounds__(256, 4) void tucker_fused_coop(
        const int* __restrict__ I, const int* __restrict__ J,
        const int* __restrict__ K,
        const float* __restrict__ U, const float* __restrict__ V,
        const float* __restrict__ W, const float* __restrict__ G,
        int* __restrict__ counts, int4* __restrict__ bins,
        int* __restrict__ ovf_cnt, int4* __restrict__ ovf,
        float* __restrict__ out, int n, int num_time, int ngroups) {
    __shared__ float4 Hs4[4][256];           // 16 KB: one H row per wave
    cg::grid_group grid = cg::this_grid();

    const int tid = (int)(blockIdx.x * 256 + threadIdx.x);
    const int nthr = (int)(gridDim.x * 256);

    // ---------------- Phase A: zero counters ----------------
    for (int c = tid; c < num_time; c += nthr) counts[c] = 0;
    if (tid == 0) *ovf_cnt = 0;
    grid.sync();

    // ---------------- Phase B: scatter ----------------
    for (int idx = tid; idx < n; idx += nthr) {
        int k = K[idx];
        int4 rec = make_int4(idx, I[idx], J[idx], k);
        int pos = atomicAdd(&counts[k], 1);
        if (pos < BIN_CAP) {
            bins[(size_t)k * BIN_CAP + pos] = rec;
        } else {
            int o = atomicAdd(ovf_cnt, 1);
            ovf[o] = rec;
        }
    }
    grid.sync();

    // ---------------- Phases C+D per k-group ----------------
    const int wave = threadIdx.x >> 6;
    const int lane = threadIdx.x & 63;
    const int qq = lane & 7;                 // q-quad
    const int s8 = lane >> 3;                // sample slot within iteration
    const float4* __restrict__ Hw = Hs4[wave];

    for (int gidx = (int)blockIdx.x; gidx < ngroups; gidx += (int)gridDim.x) {
        __syncthreads();                     // safe LDS reuse across groups
        const int k = gidx * 4 + wave;
        int m = 0;
        if (k < num_time) {
            // ---- Phase C: H[k][pq] = sum_r G[pq][r] * W[k][r] into LDS ----
            float4 wk[8];
            const float4* __restrict__ Wr = (const float4*)(W + (size_t)k * 32);
#pragma unroll
            for (int r4 = 0; r4 < 8; ++r4) wk[r4] = Wr[r4];
#pragma unroll
            for (int t = 0; t < 4; ++t) {
                const int f = lane + 64 * t; // float4 index: covers pq 4f..4f+3
                float4 o;
#pragma unroll
                for (int e = 0; e < 4; ++e) {
                    const float4* __restrict__ Gr =
                        (const float4*)(G + (size_t)(4 * f + e) * 32);
                    float a = 0.f;
#pragma unroll
                    for (int r4 = 0; r4 < 8; ++r4) {
                        float4 g = Gr[r4];
                        a += g.x * wk[r4].x + g.y * wk[r4].y +
                             g.z * wk[r4].z + g.w * wk[r4].w;
                    }
                    if (e == 0) o.x = a;
                    else if (e == 1) o.y = a;
                    else if (e == 2) o.z = a;
                    else o.w = a;
                }
                Hs4[wave][f] = o;
            }
            m = counts[k];
            m = (m < BIN_CAP) ? m : BIN_CAP;
        }

        // ---- Phase D: eval this k's samples from LDS ----
        if (k < num_time && m > 0) {
            const int iters = (m + 7) >> 3;
            const int4* __restrict__ bbase = bins + (size_t)k * BIN_CAP;

            int sc = (s8 < m) ? s8 : (m - 1);
            int4 rec = bbase[sc];

            for (int t = 0; t < iters; ++t) {
                const int s = t * 8 + s8;    // real (unclamped) index
                const float4* __restrict__ Ur =
                    (const float4*)(U + (size_t)rec.y * 32);
                float4 u[8];
#pragma unroll
                for (int p4 = 0; p4 < 8; ++p4) u[p4] = Ur[p4];
                float4 v4 = ((const float4*)(V + (size_t)rec.z * 32))[qq];

                // prefetch next iteration's record while u/v are in flight
                int sn = s + 8;
                sn = (sn < m) ? sn : (m - 1);
                int4 rec_n = bbase[sn];

                float4 acc = make_float4(0.f, 0.f, 0.f, 0.f);
#pragma unroll
                for (int p4 = 0; p4 < 8; ++p4) {
                    float4 h;
                    h = Hw[(p4 * 4 + 0) * 8 + qq];
                    acc.x += u[p4].x * h.x; acc.y += u[p4].x * h.y;
                    acc.z += u[p4].x * h.z; acc.w += u[p4].x * h.w;
                    h = Hw[(p4 * 4 + 1) * 8 + qq];
                    acc.x += u[p4].y * h.x; acc.y += u[p4].y * h.y;
                    acc.z += u[p4].y * h.z; acc.w += u[p4].y * h.w;
                    h = Hw[(p4 * 4 + 2) * 8 + qq];
                    acc.x += u[p4].z * h.x; acc.y += u[p4].z * h.y;
                    acc.z += u[p4].z * h.z; acc.w += u[p4].z * h.w;
                    h = Hw[(p4 * 4 + 3) * 8 + qq];
                    acc.x += u[p4].w * h.x; acc.y += u[p4].w * h.y;
                    acc.z += u[p4].w * h.z; acc.w += u[p4].w * h.w;
                }
                float sd = acc.x * v4.x + acc.y * v4.y + acc.z * v4.z + acc.w * v4.w;
                sd += __shfl_xor(sd, 1, 64);
                sd += __shfl_xor(sd, 2, 64);
                sd += __shfl_xor(sd, 4, 64);
                if (s < m && qq == 0) out[rec.x] = sd;
                rec = rec_n;
            }
        }

        // ---- overflow drain (expected empty): wave owning k handles it ----
        if (k < num_time) {
            const int cnt = *ovf_cnt;
            if (cnt > 0) {
                const int pg = lane >> 3;
                for (int s = 0; s < cnt; ++s) {
                    int4 rec = ovf[s];
                    if (rec.w != k) continue;           // wave-uniform test
                    const float* __restrict__ Ur2 = U + (size_t)rec.y * 32;
                    float4 acc = make_float4(0.f, 0.f, 0.f, 0.f);
#pragma unroll
                    for (int it = 0; it < 4; ++it) {
                        float4 h = Hw[lane + it * 64];
                        float up = Ur2[pg + it * 8];
                        acc.x += up * h.x; acc.y += up * h.y;
                        acc.z += up * h.z; acc.w += up * h.w;
                    }
#pragma unroll
                    for (int off = 8; off < 64; off <<= 1) {
                        acc.x += __shfl_xor(acc.x, off, 64);
                        acc.y += __shfl_xor(acc.y, off, 64);
                        acc.z += __shfl_xor(acc.z, off, 64);
                        acc.w += __shfl_xor(acc.w, off, 64);
                    }
                    float4 v4 = ((const float4*)(V + (size_t)rec.z * 32))[qq];
                    float sd = acc.x * v4.x + acc.y * v4.y +
                               acc.z * v4.z + acc.w * v4.w;
                    sd += __shfl_xor(sd, 1, 64);
                    sd += __shfl_xor(sd, 2, 64);
                    sd += __shfl_xor(sd, 4, 64);
                    if (lane == 0) out[rec.x] = sd;
                }
            }
        }
    }
}

// ===========================================================================
// Fallback pipeline (previous round): used if cooperative launch unavailable
// ===========================================================================

__device__ __forceinline__ void build_H_body(const float* __restrict__ G,
                                             const float* __restrict__ W,
                                             float* __restrict__ H,
                                             int num_time, int bblk) {
    const int pq4 = threadIdx.x;
    const int kbase = bblk * 8;

    float acc[8][4];
#pragma unroll
    for (int kk = 0; kk < 8; ++kk)
#pragma unroll
        for (int i = 0; i < 4; ++i) acc[kk][i] = 0.f;

#pragma unroll
    for (int r4 = 0; r4 < 8; ++r4) {
        float4 g[4];
#pragma unroll
        for (int i = 0; i < 4; ++i)
            g[i] = *(const float4*)(G + (size_t)(pq4 * 4 + i) * 32 + r4 * 4);
#pragma unroll
        for (int kk = 0; kk < 8; ++kk) {
            int k = kbase + kk;
            int kc = (k < num_time) ? k : (num_time - 1);
            float4 w = *(const float4*)(W + (size_t)kc * 32 + r4 * 4);
#pragma unroll
            for (int i = 0; i < 4; ++i)
                acc[kk][i] += g[i].x * w.x + g[i].y * w.y + g[i].z * w.z + g[i].w * w.w;
        }
    }

#pragma unroll
    for (int kk = 0; kk < 8; ++kk) {
        int k = kbase + kk;
        if (k < num_time) {
            float4 o = make_float4(acc[kk][0], acc[kk][1], acc[kk][2], acc[kk][3]);
            *(float4*)(H + (size_t)k * 1024 + pq4 * 4) = o;
        }
    }
}

__device__ __forceinline__ void scatter_body(const int* __restrict__ K,
                                             const int* __restrict__ I,
                                             const int* __restrict__ J,
                                             int* __restrict__ counts,
                                             int4* __restrict__ bins,
                                             int* __restrict__ ovf_cnt,
                                             int4* __restrict__ ovf,
                                             int n, int sblk, int nsblk) {
    for (int idx = sblk * 256 + (int)threadIdx.x; idx < n; idx += nsblk * 256) {
        int k = K[idx];
        int4 rec = make_int4(idx, I[idx], J[idx], k);
        int pos = atomicAdd(&counts[k], 1);
        if (pos < BIN_CAP) {
            bins[(size_t)k * BIN_CAP + pos] = rec;
        } else {
            int o = atomicAdd(ovf_cnt, 1);
            ovf[o] = rec;
        }
    }
}

__global__ __launch_bounds__(256) void fused_prepare(
        const float* __restrict__ G, const float* __restrict__ W,
        float* __restrict__ H,
        const int* __restrict__ K, const int* __restrict__ I,
        const int* __restrict__ J, int* __restrict__ counts,
        int4* __restrict__ bins, int* __restrict__ ovf_cnt,
        int4* __restrict__ ovf, int n, int num_time,
        int nbuild, int nscatter) {
    const int b = blockIdx.x;
    if (b < nbuild) {
        build_H_body(G, W, H, num_time, b);
    } else {
        scatter_body(K, I, J, counts, bins, ovf_cnt, ovf, n, b - nbuild, nscatter);
    }
}

__global__ __launch_bounds__(256) void build_H(const float* __restrict__ G,
                                               const float* __restrict__ W,
                                               float* __restrict__ H,
                                               int num_time) {
    build_H_body(G, W, H, num_time, blockIdx.x);
}

__global__ __launch_bounds__(256) void tucker_eval_grouped(
        const float* __restrict__ U, const float* __restrict__ V,
        const float* __restrict__ H, const int* __restrict__ counts,
        const int4* __restrict__ bins, float* __restrict__ out,
        int num_time, const int* __restrict__ ovf_cnt,
        const int4* __restrict__ ovf) {
    __shared__ float4 Hs4[4][256];
    const int wave = threadIdx.x >> 6;
    const int lane = threadIdx.x & 63;
    const int k = blockIdx.x * 4 + wave;
    const int qq = lane & 7;
    const int s8 = lane >> 3;

    int m = 0;
    if (k < num_time) {
        const float4* __restrict__ Hrow4 = (const float4*)(H + (size_t)k * 1024);
#pragma unroll
        for (int c = 0; c < 4; ++c)
            Hs4[wave][lane + 64 * c] = Hrow4[lane + 64 * c];
        m = counts[k];
        m = (m < BIN_CAP) ? m : BIN_CAP;
    }
    __syncthreads();

    if (k < num_time && m > 0) {
        const int iters = (m + 7) >> 3;
        const float4* __restrict__ Hw = Hs4[wave];
        const int4* __restrict__ bbase = bins + (size_t)k * BIN_CAP;

        int sc = (s8 < m) ? s8 : (m - 1);
        int4 rec = bbase[sc];

        for (int t = 0; t < iters; ++t) {
            const int s = t * 8 + s8;
            const float4* __restrict__ Ur = (const float4*)(U + (size_t)rec.y * 32);
            float4 u[8];
#pragma unroll
            for (int p4 = 0; p4 < 8; ++p4) u[p4] = Ur[p4];
            float4 v4 = ((const float4*)(V + (size_t)rec.z * 32))[qq];

            int sn = s + 8;
            sn = (sn < m) ? sn : (m - 1);
            int4 rec_n = bbase[sn];

            float4 acc = make_float4(0.f, 0.f, 0.f, 0.f);
#pragma unroll
            for (int p4 = 0; p4 < 8; ++p4) {
                float4 h;
                h = Hw[(p4 * 4 + 0) * 8 + qq];
                acc.x += u[p4].x * h.x; acc.y += u[p4].x * h.y;
                acc.z += u[p4].x * h.z; acc.w += u[p4].x * h.w;
                h = Hw[(p4 * 4 + 1) * 8 + qq];
                acc.x += u[p4].y * h.x; acc.y += u[p4].y * h.y;
                acc.z += u[p4].y * h.z; acc.w += u[p4].y * h.w;
                h = Hw[(p4 * 4 + 2) * 8 + qq];
                acc.x += u[p4].z * h.x; acc.y += u[p4].z * h.y;
                acc.z += u[p4].z * h.z; acc.w += u[p4].z * h.w;
                h = Hw[(p4 * 4 + 3) * 8 + qq];
                acc.x += u[p4].w * h.x; acc.y += u[p4].w * h.y;
                acc.z += u[p4].w * h.z; acc.w += u[p4].w * h.w;
            }
            float sd = acc.x * v4.x + acc.y * v4.y + acc.z * v4.z + acc.w * v4.w;
            sd += __shfl_xor(sd, 1, 64);
            sd += __shfl_xor(sd, 2, 64);
            sd += __shfl_xor(sd, 4, 64);
            if (s < m && qq == 0) out[rec.x] = sd;
            rec = rec_n;
        }
    }

    const int cnt = *ovf_cnt;
    if (cnt > 0) {
        const int gwave = (int)blockIdx.x * 4 + wave;
        const int nw = (int)gridDim.x * 4;
        const int pg = lane >> 3;
        for (int s = gwave; s < cnt; s += nw) {
            int4 rec = ovf[s];
            const float4* __restrict__ Hrow = (const float4*)(H + (size_t)rec.w * 1024);
            const float* __restrict__ Ur = U + (size_t)rec.y * 32;

            float4 acc = make_float4(0.f, 0.f, 0.f, 0.f);
#pragma unroll
            for (int it = 0; it < 4; ++it) {
                float4 h = Hrow[lane + it * 64];
                float up = Ur[pg + it * 8];
                acc.x += up * h.x; acc.y += up * h.y;
                acc.z += up * h.z; acc.w += up * h.w;
            }
#pragma unroll
            for (int off = 8; off < 64; off <<= 1) {
                acc.x += __shfl_xor(acc.x, off, 64);
                acc.y += __shfl_xor(acc.y, off, 64);
                acc.z += __shfl_xor(acc.z, off, 64);
                acc.w += __shfl_xor(acc.w, off, 64);
            }
            float4 v4 = ((const float4*)(V + (size_t)rec.z * 32))[qq];
            float sd = acc.x * v4.x + acc.y * v4.y + acc.z * v4.z + acc.w * v4.w;
            sd += __shfl_xor(sd, 1, 64);
            sd += __shfl_xor(sd, 2, 64);
            sd += __shfl_xor(sd, 4, 64);
            if (lane == 0) out[rec.x] = sd;
        }
    }
}

__global__ __launch_bounds__(256) void tucker_eval(const int* __restrict__ I,
                                                   const int* __restrict__ J,
                                                   const int* __restrict__ K,
                                                   const float* __restrict__ U,
                                                   const float* __restrict__ V,
                                                   const float* __restrict__ H,
                                                   float* __restrict__ out,
                                                   int n_samples) {
    const int wave = (int)((blockIdx.x * (unsigned)blockDim.x + threadIdx.x) >> 6);
    const int lane = threadIdx.x & 63;
    if (wave >= n_samples) return;
    const int i = I[wave];
    const int j = J[wave];
    const int k = K[wave];
    const int qq = lane & 7;
    const int pg = lane >> 3;
    const float4* __restrict__ Hrow = (const float4*)(H + (size_t)k * 1024);
    const float* __restrict__ Urow = U + (size_t)i * 32;
    float4 acc = make_float4(0.f, 0.f, 0.f, 0.f);
#pragma unroll
    for (int it = 0; it < 4; ++it) {
        float4 h = Hrow[lane + it * 64];
        float up = Urow[pg + it * 8];
        acc.x += up * h.x; acc.y += up * h.y;
        acc.z += up * h.z; acc.w += up * h.w;
    }
#pragma unroll
    for (int off = 8; off < 64; off <<= 1) {
        acc.x += __shfl_xor(acc.x, off, 64);
        acc.y += __shfl_xor(acc.y, off, 64);
        acc.z += __shfl_xor(acc.z, off, 64);
        acc.w += __shfl_xor(acc.w, off, 64);
    }
    float4 v4 = ((const float4*)(V + (size_t)j * 32))[qq];
    float s = acc.x * v4.x + acc.y * v4.y + acc.z * v4.z + acc.w * v4.w;
    s += __shfl_xor(s, 1, 64);
    s += __shfl_xor(s, 2, 64);
    s += __shfl_xor(s, 4, 64);
    if (lane == 0) out[wave] = s;
}

__global__ __launch_bounds__(256) void tucker_direct(const int* __restrict__ I,
                                                     const int* __restrict__ J,
                                                     const int* __restrict__ K,
                                                     const float* __restrict__ U,
                                                     const float* __restrict__ V,
                                                     const float* __restrict__ W,
                                                     const float* __restrict__ G,
                                                     float* __restrict__ out,
                                                     int n_samples) {
    __shared__ float Gc[4 * 32 * 32];
    const int n = blockIdx.x * blockDim.x + threadIdx.x;
    const bool active = (n < n_samples);
    int i = 0, j = 0, k = 0;
    if (active) { i = I[n]; j = J[n]; k = K[n]; }
    float4 w4[8];
#pragma unroll
    for (int r4 = 0; r4 < 8; ++r4)
        w4[r4] = ((const float4*)(W + (size_t)k * 32))[r4];
    float v[32];
#pragma unroll
    for (int q4 = 0; q4 < 8; ++q4) {
        float4 t = ((const float4*)(V + (size_t)j * 32))[q4];
        v[q4 * 4 + 0] = t.x; v[q4 * 4 + 1] = t.y;
        v[q4 * 4 + 2] = t.z; v[q4 * 4 + 3] = t.w;
    }
    const float* __restrict__ Urow = U + (size_t)i * 32;
    float acc = 0.f;
    for (int c = 0; c < 8; ++c) {
        __syncthreads();
#pragma unroll
        for (int t = 0; t < 4; ++t) {
            int idx = threadIdx.x + t * 256;
            ((float4*)Gc)[idx] = ((const float4*)(G + (size_t)c * 4096))[idx];
        }
        __syncthreads();
        for (int pp = 0; pp < 4; ++pp) {
            float up = Urow[c * 4 + pp];
#pragma unroll
            for (int q = 0; q < 32; ++q) {
                float t0 = 0.f;
#pragma unroll
                for (int r4 = 0; r4 < 8; ++r4) {
                    float4 g = ((const float4*)Gc)[pp * 256 + q * 8 + r4];
                    t0 += g.x * w4[r4].x + g.y * w4[r4].y + g.z * w4[r4].z + g.w * w4[r4].w;
                }
                acc += up * v[q] * t0;
            }
        }
    }
    if (active) out[n] = acc;
}

extern "C" void kernel_launch(void* const* d_in, const int* in_sizes, int n_in,
                              void* d_out, int out_size, void* d_ws, size_t ws_size,
                              hipStream_t stream) {
    const int*   I = (const int*)d_in[0];
    const int*   J = (const int*)d_in[1];
    const int*   K = (const int*)d_in[2];
    const float* U = (const float*)d_in[3];   // [NUM_USER, 32]
    const float* V = (const float*)d_in[4];   // [NUM_ITEM, 32]
    const float* W = (const float*)d_in[5];   // [NUM_TIME, 32]
    const float* G = (const float*)d_in[6];   // [32, 32, 32]
    float* out = (float*)d_out;

    const int n_samples = in_sizes[0];
    const int num_time = in_sizes[5] / 32;

    const size_t h_bytes = (size_t)num_time * 1024 * sizeof(float);
    const size_t z_bytes = (size_t)(num_time + 1) * sizeof(int);   // counts + ovf_cnt
    const size_t z_pad = (z_bytes + 15) & ~(size_t)15;
    const size_t bins_bytes = (size_t)num_time * BIN_CAP * sizeof(int4);
    const size_t ovf_bytes = (size_t)n_samples * sizeof(int4);
    const size_t need_full = h_bytes + z_pad + bins_bytes + ovf_bytes;

    if (ws_size >= need_full) {
        float* H       = (float*)d_ws;
        int*   counts  = (int*)((char*)d_ws + h_bytes);      // num_time
        int*   ovf_cnt = counts + num_time;                  // 1
        int4*  bins    = (int4*)((char*)d_ws + h_bytes + z_pad);
        int4*  ovf     = (int4*)((char*)d_ws + h_bytes + z_pad + bins_bytes);

        const int ngroups = (num_time + 3) / 4;
        int grid = (ngroups + 1) / 2;                        // 2 groups/block
        if (grid < 1) grid = 1;

        int n_arg = n_samples, nt_arg = num_time, ng_arg = ngroups;
        void* args[] = {
            (void*)&I, (void*)&J, (void*)&K,
            (void*)&U, (void*)&V, (void*)&W, (void*)&G,
            (void*)&counts, (void*)&bins, (void*)&ovf_cnt, (void*)&ovf,
            (void*)&out, (void*)&n_arg, (void*)&nt_arg, (void*)&ng_arg,
        };
        hipError_t err = hipLaunchCooperativeKernel(
            (const void*)tucker_fused_coop, dim3(grid), dim3(256), args, 0, stream);
        if (err == hipSuccess) return;
        (void)hipGetLastError();             // clear, fall through to fallback

        const int nbuild = (num_time + 7) / 8;
        const int nscatter = 512;
        hipMemsetAsync(counts, 0, z_bytes, stream);
        fused_prepare<<<nbuild + nscatter, 256, 0, stream>>>(
            G, W, H, K, I, J, counts, bins, ovf_cnt, ovf,
            n_samples, num_time, nbuild, nscatter);
        tucker_eval_grouped<<<(num_time + 3) / 4, 256, 0, stream>>>(
            U, V, H, counts, bins, out, num_time, ovf_cnt, ovf);
    } else if (ws_size >= h_bytes) {
        float* H = (float*)d_ws;
        build_H<<<(num_time + 7) / 8, 256, 0, stream>>>(G, W, H, num_time);
        const long long total_threads = (long long)n_samples * 64;
        tucker_eval<<<(int)((total_threads + 255) / 256), 256, 0, stream>>>(
            I, J, K, U, V, H, out, n_samples);
    } else {
        tucker_direct<<<(n_samples + 255) / 256, 256, 0, stream>>>(
            I, J, K, U, V, W, G, out, n_samples);
    }
}

// Round 3
// 132.143 us; speedup vs baseline: 2.9196x; 2.9196x over previous
//
#include <hip/hip_runtime.h>

// Tucker scoring: out[n] = sum_{p,q,r} U[i_n,p] V[j_n,q] W[k_n,r] G[p,q,r]
// P=Q=R=32, N=131072, num_time=5000.
//
// Round 7: revert cooperative single-kernel (regressed 2.8x: VGPR-capped
// spills + 625-block grid + per-wave G recompute = latency serialization).
// Keep the 3-dispatch structure (memset 20KB -> fused_prepare -> eval) and
// remove the eval serial gather chain:
//   (a) cooperative record staging: one coalesced 1KB load puts bin record l
//       in lane l; per-iteration records come from __shfl (no memory op).
//   (b) double-buffered U/V: iteration t+1's 8x U float4 + V quad loads are
//       issued before iteration t's FMA block, so the ~900cy HBM gather
//       latency hides under compute + TLP instead of serializing.

#define BIN_CAP 128

// ---------------------------------------------------------------------------
// build_H block body: H[k][pq] = sum_r G[pq][r] * W[k][r], 8 k per block
// ---------------------------------------------------------------------------
__device__ __forceinline__ void build_H_body(const float* __restrict__ G,
                                             const float* __restrict__ W,
                                             float* __restrict__ H,
                                             int num_time, int bblk) {
    const int pq4 = threadIdx.x;            // owns pq in [4*pq4, 4*pq4+4)
    const int kbase = bblk * 8;

    float acc[8][4];
#pragma unroll
    for (int kk = 0; kk < 8; ++kk)
#pragma unroll
        for (int i = 0; i < 4; ++i) acc[kk][i] = 0.f;

#pragma unroll
    for (int r4 = 0; r4 < 8; ++r4) {
        float4 g[4];
#pragma unroll
        for (int i = 0; i < 4; ++i)
            g[i] = *(const float4*)(G + (size_t)(pq4 * 4 + i) * 32 + r4 * 4);
#pragma unroll
        for (int kk = 0; kk < 8; ++kk) {
            int k = kbase + kk;
            int kc = (k < num_time) ? k : (num_time - 1);
            float4 w = *(const float4*)(W + (size_t)kc * 32 + r4 * 4);
#pragma unroll
            for (int i = 0; i < 4; ++i)
                acc[kk][i] += g[i].x * w.x + g[i].y * w.y + g[i].z * w.z + g[i].w * w.w;
        }
    }

#pragma unroll
    for (int kk = 0; kk < 8; ++kk) {
        int k = kbase + kk;
        if (k < num_time) {
            float4 o = make_float4(acc[kk][0], acc[kk][1], acc[kk][2], acc[kk][3]);
            *(float4*)(H + (size_t)k * 1024 + pq4 * 4) = o;
        }
    }
}

// ---------------------------------------------------------------------------
// scatter block body: bin samples by k with packed records {n, i, j, k}
// ---------------------------------------------------------------------------
__device__ __forceinline__ void scatter_body(const int* __restrict__ K,
                                             const int* __restrict__ I,
                                             const int* __restrict__ J,
                                             int* __restrict__ counts,
                                             int4* __restrict__ bins,
                                             int* __restrict__ ovf_cnt,
                                             int4* __restrict__ ovf,
                                             int n, int sblk, int nsblk) {
    for (int idx = sblk * 256 + (int)threadIdx.x; idx < n; idx += nsblk * 256) {
        int k = K[idx];
        int4 rec = make_int4(idx, I[idx], J[idx], k);
        int pos = atomicAdd(&counts[k], 1);
        if (pos < BIN_CAP) {
            bins[(size_t)k * BIN_CAP + pos] = rec;
        } else {
            int o = atomicAdd(ovf_cnt, 1);
            ovf[o] = rec;
        }
    }
}

// ---------------------------------------------------------------------------
// fused_prepare: blocks [0,nbuild) run build_H, blocks [nbuild,...) scatter.
// ---------------------------------------------------------------------------
__global__ __launch_bounds__(256) void fused_prepare(
        const float* __restrict__ G, const float* __restrict__ W,
        float* __restrict__ H,
        const int* __restrict__ K, const int* __restrict__ I,
        const int* __restrict__ J, int* __restrict__ counts,
        int4* __restrict__ bins, int* __restrict__ ovf_cnt,
        int4* __restrict__ ovf, int n, int num_time,
        int nbuild, int nscatter) {
    const int b = blockIdx.x;
    if (b < nbuild) {
        build_H_body(G, W, H, num_time, b);
    } else {
        scatter_body(K, I, J, counts, bins, ovf_cnt, ovf, n, b - nbuild, nscatter);
    }
}

// Standalone build_H (mid-tier fallback path)
__global__ __launch_bounds__(256) void build_H(const float* __restrict__ G,
                                               const float* __restrict__ W,
                                               float* __restrict__ H,
                                               int num_time) {
    build_H_body(G, W, H, num_time, blockIdx.x);
}

// ---------------------------------------------------------------------------
// eval: 256-thread block = 4 waves; wave w owns k = 4*blockIdx + w.
// H[k] (4KB) staged to LDS per wave. Lane = s8*8 + qq.
// Records staged cooperatively: one coalesced 1KB load -> lane l holds bin
// record min(l, m-1); per-iteration records distributed via __shfl.
// U/V double-buffered: next iteration's gathers issue before current FMAs.
// ---------------------------------------------------------------------------
__global__ __launch_bounds__(256) void tucker_eval_grouped(
        const float* __restrict__ U, const float* __restrict__ V,
        const float* __restrict__ H, const int* __restrict__ counts,
        const int4* __restrict__ bins, float* __restrict__ out,
        int num_time, const int* __restrict__ ovf_cnt,
        const int4* __restrict__ ovf) {
    __shared__ float4 Hs4[4][256];           // 16 KB: one H row per wave
    const int wave = threadIdx.x >> 6;
    const int lane = threadIdx.x & 63;
    const int k = blockIdx.x * 4 + wave;
    const int qq = lane & 7;                 // q-quad
    const int s8 = lane >> 3;                // sample slot within iteration

    int m = 0;
    if (k < num_time) {
        const float4* __restrict__ Hrow4 = (const float4*)(H + (size_t)k * 1024);
#pragma unroll
        for (int c = 0; c < 4; ++c)
            Hs4[wave][lane + 64 * c] = Hrow4[lane + 64 * c];
        m = counts[k];
        m = (m < BIN_CAP) ? m : BIN_CAP;
    }
    __syncthreads();

    if (k < num_time && m > 0) {
        const int iters = (m + 7) >> 3;
        const float4* __restrict__ Hw = Hs4[wave];
        const int4* __restrict__ bbase = bins + (size_t)k * BIN_CAP;

        // cooperative record stage: lane l holds record min(l, m-1)
        int4 myrec = bbase[(lane < m) ? lane : (m - 1)];

        // prologue: iteration 0 operands (record via shfl, then U/V gathers)
        int src0 = s8;                        // s8 in [0,8); clamp if m < 8
        if (src0 >= m) src0 = m - 1;
        int rn = __shfl(myrec.x, src0, 64);
        int ri = __shfl(myrec.y, src0, 64);
        int rj = __shfl(myrec.z, src0, 64);
        float4 u0[8];
        {
            const float4* __restrict__ Ur = (const float4*)(U + (size_t)ri * 32);
#pragma unroll
            for (int p4 = 0; p4 < 8; ++p4) u0[p4] = Ur[p4];
        }
        float4 v0 = ((const float4*)(V + (size_t)rj * 32))[qq];
        int outn = rn;

        for (int t = 0; t < iters; ++t) {
            // ---- issue next iteration's gathers first (hide latency) ----
            float4 u1[8];
            float4 v1;
            int outn_n = 0;
            const int tn = t + 1;
            if (tn < iters) {                 // wave-uniform branch
                int sn = tn * 8 + s8;
                if (sn >= m) sn = m - 1;
                int ni, nj;
                if (sn < 64) {                // uniform per iteration
                    outn_n = __shfl(myrec.x, sn, 64);
                    ni = __shfl(myrec.y, sn, 64);
                    nj = __shfl(myrec.z, sn, 64);
                } else {                      // m > 64: direct load (rare)
                    int4 r = bbase[sn];
                    outn_n = r.x; ni = r.y; nj = r.z;
                }
                const float4* __restrict__ Urn = (const float4*)(U + (size_t)ni * 32);
#pragma unroll
                for (int p4 = 0; p4 < 8; ++p4) u1[p4] = Urn[p4];
                v1 = ((const float4*)(V + (size_t)nj * 32))[qq];
            }

            // ---- compute current iteration from u0/v0 + LDS H ----
            float4 acc = make_float4(0.f, 0.f, 0.f, 0.f);
#pragma unroll
            for (int p4 = 0; p4 < 8; ++p4) {
                float4 h;
                h = Hw[(p4 * 4 + 0) * 8 + qq];
                acc.x += u0[p4].x * h.x; acc.y += u0[p4].x * h.y;
                acc.z += u0[p4].x * h.z; acc.w += u0[p4].x * h.w;
                h = Hw[(p4 * 4 + 1) * 8 + qq];
                acc.x += u0[p4].y * h.x; acc.y += u0[p4].y * h.y;
                acc.z += u0[p4].y * h.z; acc.w += u0[p4].y * h.w;
                h = Hw[(p4 * 4 + 2) * 8 + qq];
                acc.x += u0[p4].z * h.x; acc.y += u0[p4].z * h.y;
                acc.z += u0[p4].z * h.z; acc.w += u0[p4].z * h.w;
                h = Hw[(p4 * 4 + 3) * 8 + qq];
                acc.x += u0[p4].w * h.x; acc.y += u0[p4].w * h.y;
                acc.z += u0[p4].w * h.z; acc.w += u0[p4].w * h.w;
            }
            float sd = acc.x * v0.x + acc.y * v0.y + acc.z * v0.z + acc.w * v0.w;
            sd += __shfl_xor(sd, 1, 64);
            sd += __shfl_xor(sd, 2, 64);
            sd += __shfl_xor(sd, 4, 64);
            const int s = t * 8 + s8;        // real (unclamped) index
            if (s < m && qq == 0) out[outn] = sd;

            // ---- rotate buffers ----
            if (tn < iters) {
#pragma unroll
                for (int p4 = 0; p4 < 8; ++p4) u0[p4] = u1[p4];
                v0 = v1;
                outn = outn_n;
            }
        }
    }

    // --------- overflow tail (rare/never): wave per spill record ---------
    const int cnt = *ovf_cnt;
    if (cnt > 0) {
        const int gwave = (int)blockIdx.x * 4 + wave;
        const int nw = (int)gridDim.x * 4;
        const int pg = lane >> 3;
        for (int s = gwave; s < cnt; s += nw) {
            int4 rec = ovf[s];
            const float4* __restrict__ Hrow = (const float4*)(H + (size_t)rec.w * 1024);
            const float* __restrict__ Ur = U + (size_t)rec.y * 32;

            float4 acc = make_float4(0.f, 0.f, 0.f, 0.f);
#pragma unroll
            for (int it = 0; it < 4; ++it) {
                float4 h = Hrow[lane + it * 64];
                float up = Ur[pg + it * 8];
                acc.x += up * h.x; acc.y += up * h.y;
                acc.z += up * h.z; acc.w += up * h.w;
            }
#pragma unroll
            for (int off = 8; off < 64; off <<= 1) {
                acc.x += __shfl_xor(acc.x, off, 64);
                acc.y += __shfl_xor(acc.y, off, 64);
                acc.z += __shfl_xor(acc.z, off, 64);
                acc.w += __shfl_xor(acc.w, off, 64);
            }
            float4 v4 = ((const float4*)(V + (size_t)rec.z * 32))[qq];
            float sd = acc.x * v4.x + acc.y * v4.y + acc.z * v4.z + acc.w * v4.w;
            sd += __shfl_xor(sd, 1, 64);
            sd += __shfl_xor(sd, 2, 64);
            sd += __shfl_xor(sd, 4, 64);
            if (lane == 0) out[rec.x] = sd;
        }
    }
}

// ---------------------------------------------------------------------------
// Fallbacks for small workspace
// ---------------------------------------------------------------------------
__global__ __launch_bounds__(256) void tucker_eval(const int* __restrict__ I,
                                                   const int* __restrict__ J,
                                                   const int* __restrict__ K,
                                                   const float* __restrict__ U,
                                                   const float* __restrict__ V,
                                                   const float* __restrict__ H,
                                                   float* __restrict__ out,
                                                   int n_samples) {
    const int wave = (int)((blockIdx.x * (unsigned)blockDim.x + threadIdx.x) >> 6);
    const int lane = threadIdx.x & 63;
    if (wave >= n_samples) return;
    const int i = I[wave];
    const int j = J[wave];
    const int k = K[wave];
    const int qq = lane & 7;
    const int pg = lane >> 3;
    const float4* __restrict__ Hrow = (const float4*)(H + (size_t)k * 1024);
    const float* __restrict__ Urow = U + (size_t)i * 32;
    float4 acc = make_float4(0.f, 0.f, 0.f, 0.f);
#pragma unroll
    for (int it = 0; it < 4; ++it) {
        float4 h = Hrow[lane + it * 64];
        float up = Urow[pg + it * 8];
        acc.x += up * h.x; acc.y += up * h.y;
        acc.z += up * h.z; acc.w += up * h.w;
    }
#pragma unroll
    for (int off = 8; off < 64; off <<= 1) {
        acc.x += __shfl_xor(acc.x, off, 64);
        acc.y += __shfl_xor(acc.y, off, 64);
        acc.z += __shfl_xor(acc.z, off, 64);
        acc.w += __shfl_xor(acc.w, off, 64);
    }
    float4 v4 = ((const float4*)(V + (size_t)j * 32))[qq];
    float s = acc.x * v4.x + acc.y * v4.y + acc.z * v4.z + acc.w * v4.w;
    s += __shfl_xor(s, 1, 64);
    s += __shfl_xor(s, 2, 64);
    s += __shfl_xor(s, 4, 64);
    if (lane == 0) out[wave] = s;
}

__global__ __launch_bounds__(256) void tucker_direct(const int* __restrict__ I,
                                                     const int* __restrict__ J,
                                                     const int* __restrict__ K,
                                                     const float* __restrict__ U,
                                                     const float* __restrict__ V,
                                                     const float* __restrict__ W,
                                                     const float* __restrict__ G,
                                                     float* __restrict__ out,
                                                     int n_samples) {
    __shared__ float Gc[4 * 32 * 32];
    const int n = blockIdx.x * blockDim.x + threadIdx.x;
    const bool active = (n < n_samples);
    int i = 0, j = 0, k = 0;
    if (active) { i = I[n]; j = J[n]; k = K[n]; }
    float4 w4[8];
#pragma unroll
    for (int r4 = 0; r4 < 8; ++r4)
        w4[r4] = ((const float4*)(W + (size_t)k * 32))[r4];
    float v[32];
#pragma unroll
    for (int q4 = 0; q4 < 8; ++q4) {
        float4 t = ((const float4*)(V + (size_t)j * 32))[q4];
        v[q4 * 4 + 0] = t.x; v[q4 * 4 + 1] = t.y;
        v[q4 * 4 + 2] = t.z; v[q4 * 4 + 3] = t.w;
    }
    const float* __restrict__ Urow = U + (size_t)i * 32;
    float acc = 0.f;
    for (int c = 0; c < 8; ++c) {
        __syncthreads();
#pragma unroll
        for (int t = 0; t < 4; ++t) {
            int idx = threadIdx.x + t * 256;
            ((float4*)Gc)[idx] = ((const float4*)(G + (size_t)c * 4096))[idx];
        }
        __syncthreads();
        for (int pp = 0; pp < 4; ++pp) {
            float up = Urow[c * 4 + pp];
#pragma unroll
            for (int q = 0; q < 32; ++q) {
                float t0 = 0.f;
#pragma unroll
                for (int r4 = 0; r4 < 8; ++r4) {
                    float4 g = ((const float4*)Gc)[pp * 256 + q * 8 + r4];
                    t0 += g.x * w4[r4].x + g.y * w4[r4].y + g.z * w4[r4].z + g.w * w4[r4].w;
                }
                acc += up * v[q] * t0;
            }
        }
    }
    if (active) out[n] = acc;
}

extern "C" void kernel_launch(void* const* d_in, const int* in_sizes, int n_in,
                              void* d_out, int out_size, void* d_ws, size_t ws_size,
                              hipStream_t stream) {
    const int*   I = (const int*)d_in[0];
    const int*   J = (const int*)d_in[1];
    const int*   K = (const int*)d_in[2];
    const float* U = (const float*)d_in[3];   // [NUM_USER, 32]
    const float* V = (const float*)d_in[4];   // [NUM_ITEM, 32]
    const float* W = (const float*)d_in[5];   // [NUM_TIME, 32]
    const float* G = (const float*)d_in[6];   // [32, 32, 32]
    float* out = (float*)d_out;

    const int n_samples = in_sizes[0];
    const int num_time = in_sizes[5] / 32;

    const size_t h_bytes = (size_t)num_time * 1024 * sizeof(float);
    const size_t z_bytes = (size_t)(num_time + 1) * sizeof(int);   // counts + ovf_cnt
    const size_t z_pad = (z_bytes + 15) & ~(size_t)15;
    const size_t bins_bytes = (size_t)num_time * BIN_CAP * sizeof(int4);
    const size_t ovf_bytes = (size_t)n_samples * sizeof(int4);
    const size_t need_full = h_bytes + z_pad + bins_bytes + ovf_bytes;

    if (ws_size >= need_full) {
        float* H       = (float*)d_ws;
        int*   counts  = (int*)((char*)d_ws + h_bytes);      // num_time
        int*   ovf_cnt = counts + num_time;                  // 1
        int4*  bins    = (int4*)((char*)d_ws + h_bytes + z_pad);
        int4*  ovf     = (int4*)((char*)d_ws + h_bytes + z_pad + bins_bytes);

        const int nbuild = (num_time + 7) / 8;
        const int nscatter = 512;

        hipMemsetAsync(counts, 0, z_bytes, stream);
        fused_prepare<<<nbuild + nscatter, 256, 0, stream>>>(
            G, W, H, K, I, J, counts, bins, ovf_cnt, ovf,
            n_samples, num_time, nbuild, nscatter);
        tucker_eval_grouped<<<(num_time + 3) / 4, 256, 0, stream>>>(
            U, V, H, counts, bins, out, num_time, ovf_cnt, ovf);
    } else if (ws_size >= h_bytes) {
        float* H = (float*)d_ws;
        build_H<<<(num_time + 7) / 8, 256, 0, stream>>>(G, W, H, num_time);
        const long long total_threads = (long long)n_samples * 64;
        tucker_eval<<<(int)((total_threads + 255) / 256), 256, 0, stream>>>(
            I, J, K, U, V, H, out, n_samples);
    } else {
        tucker_direct<<<(n_samples + 255) / 256, 256, 0, stream>>>(
            I, J, K, U, V, W, G, out, n_samples);
    }
}